// Round 4
// baseline (336.620 us; speedup 1.0000x reference)
//
#include <hip/hip_runtime.h>
#include <math.h>
#include <float.h>

// Problem constants
#define NTOK 65536
#define NCB  4
#define MCODE 512
#define DIM  64

#define QST_SIZE (NTOK * NCB * DIM)        // 16777216
#define IDX_OFF  (QST_SIZE + 3)            // 16777219

#define TOK_TILE  128                      // tokens per block (32 per wave)
#define NBLOCKS   (NTOK / TOK_TILE * NCB)  // 2048

// ws layout (bytes):
//   eh  f16[2048*64]  @ 0        hi half of 512*e
//   el  f16[2048*64]  @ 262144   lo half
//   d0  f32[2048]     @ 524288   512 * sum(e^2)
//   counts int[2048]  @ 532480
//   lossSum f32       @ 540672
//   done    u32       @ 540676
#define WS_EH 0
#define WS_EL 262144
#define WS_D0 524288
#define WS_CNT 532480
#define WS_LOSS 540672
#define WS_DONE 540676

typedef _Float16 half8 __attribute__((ext_vector_type(8)));
typedef _Float16 half4 __attribute__((ext_vector_type(4)));
typedef float floatx4 __attribute__((ext_vector_type(4)));

// ---- prep: coalesced f16 hi/lo split of 512*e, d0, zero counts/loss/done ----
// 32 blocks x 256 threads; each block does 64 rows (4 passes of 16 rows).
// Lane layout per pass: row = base + (tid>>4), d4 = tid&15 -> float4 chunk.
__global__ __launch_bounds__(256) void prep_kernel(const float* __restrict__ emb,
                                                   _Float16* __restrict__ eh,
                                                   _Float16* __restrict__ el,
                                                   float* __restrict__ d0,
                                                   int* __restrict__ counts,
                                                   float* __restrict__ lossSum,
                                                   unsigned* __restrict__ done) {
    const int tid = threadIdx.x;
    const int d4  = tid & 15;
#pragma unroll
    for (int p = 0; p < 4; ++p) {
        int row = blockIdx.x * 64 + p * 16 + (tid >> 4);
        float4 v = *(const float4*)(emb + (size_t)row * DIM + d4 * 4);
        float s = v.x * v.x + v.y * v.y + v.z * v.z + v.w * v.w;
        // hi/lo split of 512*e
        half4 h, l;
        float f0 = v.x * 512.0f, f1 = v.y * 512.0f, f2 = v.z * 512.0f, f3 = v.w * 512.0f;
        h[0] = (_Float16)f0; l[0] = (_Float16)(f0 - (float)h[0]);
        h[1] = (_Float16)f1; l[1] = (_Float16)(f1 - (float)h[1]);
        h[2] = (_Float16)f2; l[2] = (_Float16)(f2 - (float)h[2]);
        h[3] = (_Float16)f3; l[3] = (_Float16)(f3 - (float)h[3]);
        *(half4*)(eh + (size_t)row * DIM + d4 * 4) = h;
        *(half4*)(el + (size_t)row * DIM + d4 * 4) = l;
        // 16-lane row sum
#pragma unroll
        for (int off = 1; off < 16; off <<= 1) s += __shfl_xor(s, off);
        if (d4 == 0) {
            d0[row] = 512.0f * s;
            counts[row] = 0;
        }
    }
    if (blockIdx.x == 0 && tid == 0) { *lossSum = 0.f; *done = 0u; }
}

// ---- main: MFMA distances + argmin + epilogue + last-block finalize ----
__global__ __launch_bounds__(256, 6) void vq_main(const float* __restrict__ x,
                                                  const float* __restrict__ emb,
                                                  const float* __restrict__ mask,
                                                  const _Float16* __restrict__ eh,
                                                  const _Float16* __restrict__ el,
                                                  const float* __restrict__ d0,
                                                  int* __restrict__ counts,
                                                  float* __restrict__ lossSum,
                                                  unsigned* __restrict__ done,
                                                  float* __restrict__ outQ,
                                                  float* __restrict__ outIdx) {
    __shared__ int   Is[TOK_TILE];
    __shared__ float wls[4];
    __shared__ int   lastFlag;

    const int tid  = threadIdx.x;
    const int c    = blockIdx.y;
    const int n0tk = blockIdx.x * TOK_TILE;
    const int lane = tid & 63;
    const int w    = tid >> 6;            // wave id 0..3
    const int col  = lane & 15;           // MFMA col (code) / row m in A
    const int quad = lane >> 4;           // 0..3

    // ---- persistent A fragments (hi/lo) straight from global ----
    // subtile s: token = w*32 + s*16 + col ; kstep ks: k = ks*32 + quad*8 + j
    half8 Ahi[2][2], Alo[2][2];
#pragma unroll
    for (int s = 0; s < 2; ++s) {
        const float* xr = x + (size_t)(n0tk + w * 32 + s * 16 + col) * (NCB * DIM) + c * DIM;
#pragma unroll
        for (int ks = 0; ks < 2; ++ks) {
            const float* p = xr + ks * 32 + quad * 8;
            float4 f0 = *(const float4*)(p);
            float4 f1 = *(const float4*)(p + 4);
            float fv[8] = {f0.x, f0.y, f0.z, f0.w, f1.x, f1.y, f1.z, f1.w};
            half8 h, l;
#pragma unroll
            for (int t = 0; t < 8; ++t) {
                _Float16 hi = (_Float16)fv[t];
                float r = fv[t] - (float)hi;
                h[t] = hi;
                l[t] = (_Float16)r;
            }
            Ahi[s][ks] = h;
            Alo[s][ks] = l;
        }
    }

    float minv[2][4];
    int   mini[2][4];
#pragma unroll
    for (int s = 0; s < 2; ++s)
#pragma unroll
        for (int r = 0; r < 4; ++r) { minv[s][r] = FLT_MAX; mini[s][r] = 0; }

    const _Float16* ehc = eh + (size_t)c * MCODE * DIM + (size_t)col * DIM + quad * 8;
    const _Float16* elc = el + (size_t)c * MCODE * DIM + (size_t)col * DIM + quad * 8;
    const float*    d0c = d0 + c * MCODE;

    // ---- sweep 32 n-tiles of 16 codes, register-double-buffered B ----
    half8 Bh0 = *(const half8*)(ehc);
    half8 Bh1 = *(const half8*)(ehc + 32);
    half8 Bl0 = *(const half8*)(elc);
    half8 Bl1 = *(const half8*)(elc + 32);
    float d0v = d0c[col];

    for (int nt = 0; nt < 32; ++nt) {
        const int n = nt * 16 + col;
        half8 Ch0, Ch1, Cl0, Cl1; float d0n;
        if (nt < 31) {
            const _Float16* bh = ehc + (size_t)(nt + 1) * 16 * DIM;
            const _Float16* bl = elc + (size_t)(nt + 1) * 16 * DIM;
            Ch0 = *(const half8*)(bh);
            Ch1 = *(const half8*)(bh + 32);
            Cl0 = *(const half8*)(bl);
            Cl1 = *(const half8*)(bl + 32);
            d0n = d0c[(nt + 1) * 16 + col];
        }
#pragma unroll
        for (int s = 0; s < 2; ++s) {
            floatx4 acc = {0.f, 0.f, 0.f, 0.f};
            acc = __builtin_amdgcn_mfma_f32_16x16x32_f16(Ahi[s][0], Bh0, acc, 0, 0, 0);
            acc = __builtin_amdgcn_mfma_f32_16x16x32_f16(Ahi[s][1], Bh1, acc, 0, 0, 0);
            acc = __builtin_amdgcn_mfma_f32_16x16x32_f16(Alo[s][0], Bh0, acc, 0, 0, 0);
            acc = __builtin_amdgcn_mfma_f32_16x16x32_f16(Alo[s][1], Bh1, acc, 0, 0, 0);
            acc = __builtin_amdgcn_mfma_f32_16x16x32_f16(Ahi[s][0], Bl0, acc, 0, 0, 0);
            acc = __builtin_amdgcn_mfma_f32_16x16x32_f16(Ahi[s][1], Bl1, acc, 0, 0, 0);
#pragma unroll
            for (int r = 0; r < 4; ++r) {
                float dv = fmaf(-2.f, acc[r], d0v);   // 512*(e2 - 2 x.e)
                if (dv < minv[s][r]) { minv[s][r] = dv; mini[s][r] = n; }
            }
        }
        if (nt < 31) {
            Bh0 = Ch0; Bh1 = Ch1; Bl0 = Cl0; Bl1 = Cl1; d0v = d0n;
        }
    }

    // ---- reduce across the 16 col-lanes of each quad (first-min tie-break) ----
#pragma unroll
    for (int off = 1; off < 16; off <<= 1) {
#pragma unroll
        for (int s = 0; s < 2; ++s)
#pragma unroll
            for (int r = 0; r < 4; ++r) {
                float ov = __shfl_xor(minv[s][r], off);
                int   oi = __shfl_xor(mini[s][r], off);
                if (ov < minv[s][r] || (ov == minv[s][r] && oi < mini[s][r])) {
                    minv[s][r] = ov; mini[s][r] = oi;
                }
            }
    }
    if (col == 0) {
        // token = w*32 + s*16 + quad*4 + r
#pragma unroll
        for (int s = 0; s < 2; ++s)
#pragma unroll
            for (int r = 0; r < 4; ++r)
                Is[w * 32 + s * 16 + quad * 4 + r] = mini[s][r];
    }
    __syncthreads();

    // ---- indices + histogram ----
    if (tid < TOK_TILE) {
        int idx = Is[tid];
        atomicAdd(&counts[c * MCODE + idx], 1);
        outIdx[(size_t)(n0tk + tid) * NCB + c] = (float)idx;
    }

    // ---- quantized_st + loss (fp32 x re-read, fp32 emb gather) ----
    float lloss = 0.f;
#pragma unroll
    for (int i = 0; i < 8; ++i) {
        int q = tid + i * 256;
        int tok = q >> 4, d4 = q & 15;
        int idx = Is[tok];
        float mv = mask[(size_t)(n0tk + tok) * NCB + c];
        float4 e4 = *(const float4*)(emb + ((size_t)c * MCODE + idx) * DIM + d4 * 4);
        float4 x4 = *(const float4*)(x + (size_t)(n0tk + tok) * (NCB * DIM) + c * DIM + d4 * 4);
        float qx = e4.x * mv, qy = e4.y * mv, qz = e4.z * mv, qw = e4.w * mv;
        float4 o;
        o.x = x4.x + (qx - x4.x);
        o.y = x4.y + (qy - x4.y);
        o.z = x4.z + (qz - x4.z);
        o.w = x4.w + (qw - x4.w);
        *(float4*)(outQ + (size_t)(n0tk + tok) * (NCB * DIM) + c * DIM + d4 * 4) = o;
        float dx = x4.x - qx, dy = x4.y - qy, dz = x4.z - qz, dw = x4.w - qw;
        lloss += dx * dx + dy * dy + dz * dz + dw * dw;
    }
#pragma unroll
    for (int off = 32; off > 0; off >>= 1) lloss += __shfl_xor(lloss, off);
    if ((tid & 63) == 0) wls[tid >> 6] = lloss;
    __syncthreads();
    if (tid == 0) {
        float s = wls[0] + wls[1] + wls[2] + wls[3];
        atomicAdd(lossSum, s);
        __threadfence();
        unsigned o = atomicAdd(done, 1u);
        lastFlag = (o == (unsigned)(NBLOCKS - 1)) ? 1 : 0;
    }
    __syncthreads();

    // ---- last block computes losses + perplexity ----
    if (lastFlag) {
        float s = 0.f;
#pragma unroll
        for (int i = 0; i < 8; ++i) {
            int j = tid + i * 256;
            int cnt = atomicAdd(&counts[j], 0);      // coherent read
            float p = (float)cnt * (1.0f / 65536.0f);
            s += p * logf(p + 1e-10f);
        }
#pragma unroll
        for (int off = 32; off > 0; off >>= 1) s += __shfl_xor(s, off);
        if ((tid & 63) == 0) wls[tid >> 6] = s;
        __syncthreads();
        if (tid == 0) {
            float tot = wls[0] + wls[1] + wls[2] + wls[3];
            float L = atomicAdd(lossSum, 0.f) * (1.0f / (float)QST_SIZE);
            outQ[QST_SIZE + 0] = 0.25f * L;   // commitment_loss
            outQ[QST_SIZE + 1] = L;           // codebook_loss
            outQ[QST_SIZE + 2] = expf(-tot);  // perplexity
        }
    }
}

extern "C" void kernel_launch(void* const* d_in, const int* in_sizes, int n_in,
                              void* d_out, int out_size, void* d_ws, size_t ws_size,
                              hipStream_t stream) {
    const float* x    = (const float*)d_in[0];
    const float* emb  = (const float*)d_in[1];
    const float* mask = (const float*)d_in[2];
    float* out = (float*)d_out;

    _Float16* eh     = (_Float16*)((char*)d_ws + WS_EH);
    _Float16* el     = (_Float16*)((char*)d_ws + WS_EL);
    float* d0        = (float*)((char*)d_ws + WS_D0);
    int*   counts    = (int*)((char*)d_ws + WS_CNT);
    float* lossSum   = (float*)((char*)d_ws + WS_LOSS);
    unsigned* doneCt = (unsigned*)((char*)d_ws + WS_DONE);

    prep_kernel<<<dim3(32), dim3(256), 0, stream>>>(emb, eh, el, d0, counts, lossSum, doneCt);
    vq_main<<<dim3(NTOK / TOK_TILE, NCB), dim3(256), 0, stream>>>(
        x, emb, mask, eh, el, d0, counts, lossSum, doneCt, out, out + IDX_OFF);
}

// Round 5
// 277.186 us; speedup vs baseline: 1.2144x; 1.2144x over previous
//
#include <hip/hip_runtime.h>
#include <math.h>
#include <float.h>

// Problem constants
#define NTOK 65536
#define NCB  4
#define MCODE 512
#define DIM  64

#define QST_SIZE (NTOK * NCB * DIM)        // 16777216
#define IDX_OFF  (QST_SIZE + 3)            // 16777219

#define TOK_TILE  256                      // tokens per block
#define NBLOCKS   (NTOK / TOK_TILE * NCB)  // 1024

// ws layout (bytes):
//   eh  f16[2048*64]  @ 0        hi half of 512*e
//   el  f16[2048*64]  @ 262144   lo half
//   d0  f32[2048]     @ 524288   512 * sum(e^2)
//   counts int[2048]  @ 532480
//   lossSum f32       @ 540672
//   done    u32       @ 540676
#define WS_EH 0
#define WS_EL 262144
#define WS_D0 524288
#define WS_CNT 532480
#define WS_LOSS 540672
#define WS_DONE 540676

typedef _Float16 half8 __attribute__((ext_vector_type(8)));
typedef _Float16 half4 __attribute__((ext_vector_type(4)));
typedef float floatx4 __attribute__((ext_vector_type(4)));

// ---- prep: coalesced f16 hi/lo split of 512*e, d0, zero counts/loss/done ----
__global__ __launch_bounds__(256) void prep_kernel(const float* __restrict__ emb,
                                                   _Float16* __restrict__ eh,
                                                   _Float16* __restrict__ el,
                                                   float* __restrict__ d0,
                                                   int* __restrict__ counts,
                                                   float* __restrict__ lossSum,
                                                   unsigned* __restrict__ done) {
    const int tid = threadIdx.x;
    const int d4  = tid & 15;
#pragma unroll
    for (int p = 0; p < 4; ++p) {
        int row = blockIdx.x * 64 + p * 16 + (tid >> 4);
        float4 v = *(const float4*)(emb + (size_t)row * DIM + d4 * 4);
        float s = v.x * v.x + v.y * v.y + v.z * v.z + v.w * v.w;
        half4 h, l;
        float f0 = v.x * 512.0f, f1 = v.y * 512.0f, f2 = v.z * 512.0f, f3 = v.w * 512.0f;
        h[0] = (_Float16)f0; l[0] = (_Float16)(f0 - (float)h[0]);
        h[1] = (_Float16)f1; l[1] = (_Float16)(f1 - (float)h[1]);
        h[2] = (_Float16)f2; l[2] = (_Float16)(f2 - (float)h[2]);
        h[3] = (_Float16)f3; l[3] = (_Float16)(f3 - (float)h[3]);
        *(half4*)(eh + (size_t)row * DIM + d4 * 4) = h;
        *(half4*)(el + (size_t)row * DIM + d4 * 4) = l;
#pragma unroll
        for (int off = 1; off < 16; off <<= 1) s += __shfl_xor(s, off);
        if (d4 == 0) {
            d0[row] = 512.0f * s;
            counts[row] = 0;
        }
    }
    if (blockIdx.x == 0 && tid == 0) { *lossSum = 0.f; *done = 0u; }
}

// ---- main: code-stationary MFMA distances + argmin + epilogue + finalize ----
// 512 threads = 8 waves; wave w owns codes [w*64, w*64+64) in registers.
// Tokens stream through the B operand: D[row=code(quad*4+r)][col=token(lane&15)].
__global__ __launch_bounds__(512, 3) void vq_main(const float* __restrict__ x,
                                                  const float* __restrict__ emb,
                                                  const float* __restrict__ mask,
                                                  const _Float16* __restrict__ eh,
                                                  const _Float16* __restrict__ el,
                                                  const float* __restrict__ d0,
                                                  int* __restrict__ counts,
                                                  float* __restrict__ lossSum,
                                                  unsigned* __restrict__ done,
                                                  float* __restrict__ outQ,
                                                  float* __restrict__ outIdx) {
    __shared__ float candV[8][TOK_TILE];   // per-wave best dist per token
    __shared__ int   candI[8][TOK_TILE];
    __shared__ int   Is[TOK_TILE];
    __shared__ float wls[8];
    __shared__ int   lastFlag;

    const int tid  = threadIdx.x;
    const int c    = blockIdx.y;
    const int n0tk = blockIdx.x * TOK_TILE;
    const int lane = tid & 63;
    const int w    = tid >> 6;            // wave 0..7
    const int col  = lane & 15;           // token col in D / row sel in A,B operands
    const int quad = lane >> 4;           // 0..3

    // ---- persistent A fragments: this wave's 64 codes (hi/lo), loaded once ----
    // t-tile t: code = w*64 + t*16 + col ; kstep ks: k = ks*32 + quad*8 + j
    half8 Ehi[4][2], Elo[4][2];
    float d0v[4][4];
    {
        const _Float16* ehB = eh + (size_t)c * MCODE * DIM;
        const _Float16* elB = el + (size_t)c * MCODE * DIM;
        const float*    d0B = d0 + c * MCODE + w * 64;
#pragma unroll
        for (int t = 0; t < 4; ++t) {
            size_t row = (size_t)(w * 64 + t * 16 + col) * DIM + quad * 8;
#pragma unroll
            for (int ks = 0; ks < 2; ++ks) {
                Ehi[t][ks] = *(const half8*)(ehB + row + ks * 32);
                Elo[t][ks] = *(const half8*)(elB + row + ks * 32);
            }
#pragma unroll
            for (int r = 0; r < 4; ++r)
                d0v[t][r] = d0B[t * 16 + quad * 4 + r];
        }
    }

    // ---- stream 16 token-subtiles; x prefetched one subtile ahead ----
    // subtile s: token = n0tk + s*16 + col ; per lane 16 floats (k = ks*32+quad*8+j)
    const float* xq = x + (size_t)(n0tk + col) * (NCB * DIM) + c * DIM + quad * 8;
    float4 r0 = *(const float4*)(xq);
    float4 r1 = *(const float4*)(xq + 4);
    float4 r2 = *(const float4*)(xq + 32);
    float4 r3 = *(const float4*)(xq + 36);

    for (int s = 0; s < 16; ++s) {
        float4 n0_, n1_, n2_, n3_;
        if (s < 15) {
            const float* xn = xq + (size_t)(s + 1) * 16 * (NCB * DIM);
            n0_ = *(const float4*)(xn);
            n1_ = *(const float4*)(xn + 4);
            n2_ = *(const float4*)(xn + 32);
            n3_ = *(const float4*)(xn + 36);
        }
        // convert this subtile's token fragment to f16 hi/lo
        float fv[16] = {r0.x, r0.y, r0.z, r0.w, r1.x, r1.y, r1.z, r1.w,
                        r2.x, r2.y, r2.z, r2.w, r3.x, r3.y, r3.z, r3.w};
        half8 Bhi[2], Blo[2];
#pragma unroll
        for (int ks = 0; ks < 2; ++ks)
#pragma unroll
            for (int j = 0; j < 8; ++j) {
                float f = fv[ks * 8 + j + ks * 0 + (ks ? 0 : 0)];
                // fv layout: [0..7] = ks0, [8..15] = ks1
                f = fv[ks * 8 + j];
                _Float16 hi = (_Float16)f;
                Bhi[ks][j] = hi;
                Blo[ks][j] = (_Float16)(f - (float)hi);
            }

        float minv = FLT_MAX;
        int   mini = 0;
#pragma unroll
        for (int t = 0; t < 4; ++t) {
            floatx4 acc = {0.f, 0.f, 0.f, 0.f};
            acc = __builtin_amdgcn_mfma_f32_16x16x32_f16(Ehi[t][0], Bhi[0], acc, 0, 0, 0);
            acc = __builtin_amdgcn_mfma_f32_16x16x32_f16(Ehi[t][1], Bhi[1], acc, 0, 0, 0);
            acc = __builtin_amdgcn_mfma_f32_16x16x32_f16(Ehi[t][0], Blo[0], acc, 0, 0, 0);
            acc = __builtin_amdgcn_mfma_f32_16x16x32_f16(Ehi[t][1], Blo[1], acc, 0, 0, 0);
            acc = __builtin_amdgcn_mfma_f32_16x16x32_f16(Elo[t][0], Bhi[0], acc, 0, 0, 0);
            acc = __builtin_amdgcn_mfma_f32_16x16x32_f16(Elo[t][1], Bhi[1], acc, 0, 0, 0);
#pragma unroll
            for (int r = 0; r < 4; ++r) {
                float dv = fmaf(-2.f, acc[r], d0v[t][r]);
                int   ci = w * 64 + t * 16 + quad * 4 + r;
                if (dv < minv) { minv = dv; mini = ci; }   // idx ascending in (t,r)
            }
        }
        // cross-quad reduce (codes partitioned over lanes col, col+16, col+32, col+48)
#pragma unroll
        for (int off = 16; off < 64; off <<= 1) {
            float ov = __shfl_xor(minv, off);
            int   oi = __shfl_xor(mini, off);
            if (ov < minv || (ov == minv && oi < mini)) { minv = ov; mini = oi; }
        }
        if (quad == 0) {
            candV[w][s * 16 + col] = minv;
            candI[w][s * 16 + col] = mini;
        }
        r0 = n0_; r1 = n1_; r2 = n2_; r3 = n3_;
    }
    __syncthreads();

    // ---- combine 8 waves' candidates; indices + histogram ----
    if (tid < TOK_TILE) {
        float bv = candV[0][tid];
        int   bi = candI[0][tid];
#pragma unroll
        for (int wv = 1; wv < 8; ++wv) {
            float v = candV[wv][tid];
            int   i = candI[wv][tid];
            if (v < bv) { bv = v; bi = i; }   // idx ascends with wv: strict < = first-min
        }
        Is[tid] = bi;
        atomicAdd(&counts[c * MCODE + bi], 1);
        outIdx[(size_t)(n0tk + tid) * NCB + c] = (float)bi;
    }
    __syncthreads();

    // ---- quantized_st + loss (fp32 x re-read, fp32 emb gather) ----
    float lloss = 0.f;
#pragma unroll
    for (int i = 0; i < 8; ++i) {
        int q = tid + i * 512;
        int tok = q >> 4, d4 = q & 15;
        int idx = Is[tok];
        float mv = mask[(size_t)(n0tk + tok) * NCB + c];
        float4 e4 = *(const float4*)(emb + ((size_t)c * MCODE + idx) * DIM + d4 * 4);
        float4 x4 = *(const float4*)(x + (size_t)(n0tk + tok) * (NCB * DIM) + c * DIM + d4 * 4);
        float qx = e4.x * mv, qy = e4.y * mv, qz = e4.z * mv, qw = e4.w * mv;
        float4 o;
        o.x = x4.x + (qx - x4.x);
        o.y = x4.y + (qy - x4.y);
        o.z = x4.z + (qz - x4.z);
        o.w = x4.w + (qw - x4.w);
        *(float4*)(outQ + (size_t)(n0tk + tok) * (NCB * DIM) + c * DIM + d4 * 4) = o;
        float dx = x4.x - qx, dy = x4.y - qy, dz = x4.z - qz, dw = x4.w - qw;
        lloss += dx * dx + dy * dy + dz * dz + dw * dw;
    }
#pragma unroll
    for (int off = 32; off > 0; off >>= 1) lloss += __shfl_xor(lloss, off);
    if (lane == 0) wls[w] = lloss;
    __syncthreads();
    if (tid == 0) {
        float s = 0.f;
#pragma unroll
        for (int i = 0; i < 8; ++i) s += wls[i];
        atomicAdd(lossSum, s);
        __threadfence();
        unsigned o = atomicAdd(done, 1u);
        lastFlag = (o == (unsigned)(NBLOCKS - 1)) ? 1 : 0;
    }
    __syncthreads();

    // ---- last block computes losses + perplexity ----
    if (lastFlag) {
        float s = 0.f;
#pragma unroll
        for (int i = 0; i < 4; ++i) {
            int j = tid + i * 512;
            int cnt = atomicAdd(&counts[j], 0);      // coherent read
            float p = (float)cnt * (1.0f / 65536.0f);
            s += p * logf(p + 1e-10f);
        }
#pragma unroll
        for (int off = 32; off > 0; off >>= 1) s += __shfl_xor(s, off);
        if (lane == 0) wls[w] = s;
        __syncthreads();
        if (tid == 0) {
            float tot = 0.f;
#pragma unroll
            for (int i = 0; i < 8; ++i) tot += wls[i];
            float L = atomicAdd(lossSum, 0.f) * (1.0f / (float)QST_SIZE);
            outQ[QST_SIZE + 0] = 0.25f * L;   // commitment_loss
            outQ[QST_SIZE + 1] = L;           // codebook_loss
            outQ[QST_SIZE + 2] = expf(-tot);  // perplexity
        }
    }
}

extern "C" void kernel_launch(void* const* d_in, const int* in_sizes, int n_in,
                              void* d_out, int out_size, void* d_ws, size_t ws_size,
                              hipStream_t stream) {
    const float* x    = (const float*)d_in[0];
    const float* emb  = (const float*)d_in[1];
    const float* mask = (const float*)d_in[2];
    float* out = (float*)d_out;

    _Float16* eh     = (_Float16*)((char*)d_ws + WS_EH);
    _Float16* el     = (_Float16*)((char*)d_ws + WS_EL);
    float* d0        = (float*)((char*)d_ws + WS_D0);
    int*   counts    = (int*)((char*)d_ws + WS_CNT);
    float* lossSum   = (float*)((char*)d_ws + WS_LOSS);
    unsigned* doneCt = (unsigned*)((char*)d_ws + WS_DONE);

    prep_kernel<<<dim3(32), dim3(256), 0, stream>>>(emb, eh, el, d0, counts, lossSum, doneCt);
    vq_main<<<dim3(NTOK / TOK_TILE, NCB), dim3(512), 0, stream>>>(
        x, emb, mask, eh, el, d0, counts, lossSum, doneCt, out, out + IDX_OFF);
}

// Round 6
// 223.439 us; speedup vs baseline: 1.5065x; 1.2405x over previous
//
#include <hip/hip_runtime.h>
#include <math.h>
#include <float.h>

// Problem constants
#define NTOK 65536
#define NCB  4
#define MCODE 512
#define DIM  64

#define QST_SIZE (NTOK * NCB * DIM)        // 16777216
#define IDX_OFF  (QST_SIZE + 3)            // 16777219

#define TOK_TILE  512                      // tokens per block (64 per wave, 8 waves)
#define NBLOCKS   (NTOK / TOK_TILE * NCB)  // 512

// LDS row stride for codebook: 64 f16 data + 8 pad = 72 halfs (144 B)
#define EROW 72

// ws layout (bytes):
//   eh  f16[2048*64]  @ 0        hi half of 512*e
//   el  f16[2048*64]  @ 262144   lo half
//   d0  f32[2048]     @ 524288   512 * sum(e^2)
//   counts int[2048]  @ 532480
//   lossSum f32       @ 540672
//   done    u32       @ 540676
#define WS_EH 0
#define WS_EL 262144
#define WS_D0 524288
#define WS_CNT 532480
#define WS_LOSS 540672
#define WS_DONE 540676

typedef _Float16 half8 __attribute__((ext_vector_type(8)));
typedef _Float16 half4 __attribute__((ext_vector_type(4)));
typedef float floatx4 __attribute__((ext_vector_type(4)));

// ---- prep: coalesced f16 hi/lo split of 512*e, d0, zero counts/loss/done ----
__global__ __launch_bounds__(256) void prep_kernel(const float* __restrict__ emb,
                                                   _Float16* __restrict__ eh,
                                                   _Float16* __restrict__ el,
                                                   float* __restrict__ d0,
                                                   int* __restrict__ counts,
                                                   float* __restrict__ lossSum,
                                                   unsigned* __restrict__ done) {
    const int tid = threadIdx.x;
    const int d4  = tid & 15;
#pragma unroll
    for (int p = 0; p < 4; ++p) {
        int row = blockIdx.x * 64 + p * 16 + (tid >> 4);
        float4 v = *(const float4*)(emb + (size_t)row * DIM + d4 * 4);
        float s = v.x * v.x + v.y * v.y + v.z * v.z + v.w * v.w;
        half4 h, l;
        float f0 = v.x * 512.0f, f1 = v.y * 512.0f, f2 = v.z * 512.0f, f3 = v.w * 512.0f;
        h[0] = (_Float16)f0; l[0] = (_Float16)(f0 - (float)h[0]);
        h[1] = (_Float16)f1; l[1] = (_Float16)(f1 - (float)h[1]);
        h[2] = (_Float16)f2; l[2] = (_Float16)(f2 - (float)h[2]);
        h[3] = (_Float16)f3; l[3] = (_Float16)(f3 - (float)h[3]);
        *(half4*)(eh + (size_t)row * DIM + d4 * 4) = h;
        *(half4*)(el + (size_t)row * DIM + d4 * 4) = l;
#pragma unroll
        for (int off = 1; off < 16; off <<= 1) s += __shfl_xor(s, off);
        if (d4 == 0) {
            d0[row] = 512.0f * s;
            counts[row] = 0;
        }
    }
    if (blockIdx.x == 0 && tid == 0) { *lossSum = 0.f; *done = 0u; }
}

// ---- main: codebook-in-LDS, X-stationary MFMA, barrier-free inner loop ----
// 512 threads = 8 waves; wave w owns tokens [w*64, w*64+64) as A-fragments.
// Codes stream through B from LDS. D[row=token quad*4+r][col=code lane&15].
__global__ __launch_bounds__(512, 2) void vq_main(const float* __restrict__ x,
                                                  const float* __restrict__ emb,
                                                  const float* __restrict__ mask,
                                                  const _Float16* __restrict__ eh,
                                                  const _Float16* __restrict__ el,
                                                  const float* __restrict__ d0,
                                                  int* __restrict__ counts,
                                                  float* __restrict__ lossSum,
                                                  unsigned* __restrict__ done,
                                                  float* __restrict__ outQ,
                                                  float* __restrict__ outIdx) {
    __shared__ _Float16 EHs[MCODE * EROW];   // 73728 B
    __shared__ _Float16 ELs[MCODE * EROW];   // 73728 B
    __shared__ float    d0s[MCODE];          // 2 KB
    __shared__ int      Is[TOK_TILE];        // 2 KB
    __shared__ float    wls[8];
    __shared__ int      lastFlag;

    const int tid  = threadIdx.x;
    const int c    = blockIdx.y;
    const int n0tk = blockIdx.x * TOK_TILE;
    const int lane = tid & 63;
    const int w    = tid >> 6;            // wave 0..7
    const int col  = lane & 15;
    const int quad = lane >> 4;           // 0..3

    // ---- stage codebook hi/lo into LDS (coalesced 16-B chunks) + d0 ----
    {
        const _Float16* ehc = eh + (size_t)c * MCODE * DIM;
        const _Float16* elc = el + (size_t)c * MCODE * DIM;
#pragma unroll
        for (int i = 0; i < 8; ++i) {
            int g = tid + i * 512;            // 0..4095 chunk id
            int code = g >> 3, j = g & 7;     // 8 chunks of 8 halfs per row
            *(half8*)(EHs + code * EROW + j * 8) = *(const half8*)(ehc + code * 64 + j * 8);
            *(half8*)(ELs + code * EROW + j * 8) = *(const half8*)(elc + code * 64 + j * 8);
        }
        d0s[tid] = d0[c * MCODE + tid];
    }

    // ---- persistent A fragments (hi/lo) from global (one-time scatter) ----
    // subtile s: token = w*64 + s*16 + col ; kstep ks: k = ks*32 + quad*8 + j
    half8 Ahi[4][2], Alo[4][2];
#pragma unroll
    for (int s = 0; s < 4; ++s) {
        const float* xr = x + (size_t)(n0tk + w * 64 + s * 16 + col) * (NCB * DIM) + c * DIM;
#pragma unroll
        for (int ks = 0; ks < 2; ++ks) {
            const float* p = xr + ks * 32 + quad * 8;
            float4 f0 = *(const float4*)(p);
            float4 f1 = *(const float4*)(p + 4);
            float fv[8] = {f0.x, f0.y, f0.z, f0.w, f1.x, f1.y, f1.z, f1.w};
            half8 h, l;
#pragma unroll
            for (int t = 0; t < 8; ++t) {
                _Float16 hi = (_Float16)fv[t];
                float r = fv[t] - (float)hi;
                h[t] = hi;
                l[t] = (_Float16)r;
            }
            Ahi[s][ks] = h;
            Alo[s][ks] = l;
        }
    }
    __syncthreads();   // LDS codebook ready

    float minv[4][4];
    int   mini[4][4];
#pragma unroll
    for (int s = 0; s < 4; ++s)
#pragma unroll
        for (int r = 0; r < 4; ++r) { minv[s][r] = FLT_MAX; mini[s][r] = 0; }

    // ---- barrier-free sweep of 32 code-tiles from LDS, 1-deep prefetch ----
    half8 Bh0 = *(const half8*)(EHs + col * EROW + quad * 8);
    half8 Bh1 = *(const half8*)(EHs + col * EROW + 32 + quad * 8);
    half8 Bl0 = *(const half8*)(ELs + col * EROW + quad * 8);
    half8 Bl1 = *(const half8*)(ELs + col * EROW + 32 + quad * 8);
    float d0v = d0s[col];

    for (int nt = 0; nt < 32; ++nt) {
        half8 Ch0, Ch1, Cl0, Cl1; float d0n;
        if (nt < 31) {
            int rw = (nt + 1) * 16 + col;
            Ch0 = *(const half8*)(EHs + rw * EROW + quad * 8);
            Ch1 = *(const half8*)(EHs + rw * EROW + 32 + quad * 8);
            Cl0 = *(const half8*)(ELs + rw * EROW + quad * 8);
            Cl1 = *(const half8*)(ELs + rw * EROW + 32 + quad * 8);
            d0n = d0s[rw];
        }
        const int n = nt * 16 + col;
#pragma unroll
        for (int s = 0; s < 4; ++s) {
            floatx4 acc = {0.f, 0.f, 0.f, 0.f};
            acc = __builtin_amdgcn_mfma_f32_16x16x32_f16(Ahi[s][0], Bh0, acc, 0, 0, 0);
            acc = __builtin_amdgcn_mfma_f32_16x16x32_f16(Ahi[s][1], Bh1, acc, 0, 0, 0);
            acc = __builtin_amdgcn_mfma_f32_16x16x32_f16(Alo[s][0], Bh0, acc, 0, 0, 0);
            acc = __builtin_amdgcn_mfma_f32_16x16x32_f16(Alo[s][1], Bh1, acc, 0, 0, 0);
            acc = __builtin_amdgcn_mfma_f32_16x16x32_f16(Ahi[s][0], Bl0, acc, 0, 0, 0);
            acc = __builtin_amdgcn_mfma_f32_16x16x32_f16(Ahi[s][1], Bl1, acc, 0, 0, 0);
#pragma unroll
            for (int r = 0; r < 4; ++r) {
                float dv = fmaf(-2.f, acc[r], d0v);   // 512*(e2 - 2 x.e)
                if (dv < minv[s][r]) { minv[s][r] = dv; mini[s][r] = n; }
            }
        }
        if (nt < 31) {
            Bh0 = Ch0; Bh1 = Ch1; Bl0 = Cl0; Bl1 = Cl1; d0v = d0n;
        }
    }

    // ---- reduce across the 16 col-lanes of each quad (first-min tie-break) ----
#pragma unroll
    for (int off = 1; off < 16; off <<= 1) {
#pragma unroll
        for (int s = 0; s < 4; ++s)
#pragma unroll
            for (int r = 0; r < 4; ++r) {
                float ov = __shfl_xor(minv[s][r], off);
                int   oi = __shfl_xor(mini[s][r], off);
                if (ov < minv[s][r] || (ov == minv[s][r] && oi < mini[s][r])) {
                    minv[s][r] = ov; mini[s][r] = oi;
                }
            }
    }
    if (col == 0) {
        // token = w*64 + s*16 + quad*4 + r
#pragma unroll
        for (int s = 0; s < 4; ++s)
#pragma unroll
            for (int r = 0; r < 4; ++r)
                Is[w * 64 + s * 16 + quad * 4 + r] = mini[s][r];
    }
    __syncthreads();

    // ---- indices + histogram ----
    {
        int idx = Is[tid];
        atomicAdd(&counts[c * MCODE + idx], 1);
        outIdx[(size_t)(n0tk + tid) * NCB + c] = (float)idx;
    }

    // ---- quantized_st + loss (fp32 x re-read, fp32 emb gather) ----
    float lloss = 0.f;
#pragma unroll
    for (int i = 0; i < 16; ++i) {
        int q = tid + i * 512;
        int tok = q >> 4, d4 = q & 15;
        int idx = Is[tok];
        float mv = mask[(size_t)(n0tk + tok) * NCB + c];
        float4 e4 = *(const float4*)(emb + ((size_t)c * MCODE + idx) * DIM + d4 * 4);
        float4 x4 = *(const float4*)(x + (size_t)(n0tk + tok) * (NCB * DIM) + c * DIM + d4 * 4);
        float qx = e4.x * mv, qy = e4.y * mv, qz = e4.z * mv, qw = e4.w * mv;
        float4 o;
        o.x = x4.x + (qx - x4.x);
        o.y = x4.y + (qy - x4.y);
        o.z = x4.z + (qz - x4.z);
        o.w = x4.w + (qw - x4.w);
        *(float4*)(outQ + (size_t)(n0tk + tok) * (NCB * DIM) + c * DIM + d4 * 4) = o;
        float dx = x4.x - qx, dy = x4.y - qy, dz = x4.z - qz, dw = x4.w - qw;
        lloss += dx * dx + dy * dy + dz * dz + dw * dw;
    }
#pragma unroll
    for (int off = 32; off > 0; off >>= 1) lloss += __shfl_xor(lloss, off);
    if (lane == 0) wls[w] = lloss;
    __syncthreads();
    if (tid == 0) {
        float s = 0.f;
#pragma unroll
        for (int i = 0; i < 8; ++i) s += wls[i];
        atomicAdd(lossSum, s);
        __threadfence();
        unsigned o = atomicAdd(done, 1u);
        lastFlag = (o == (unsigned)(NBLOCKS - 1)) ? 1 : 0;
    }
    __syncthreads();

    // ---- last block computes losses + perplexity ----
    if (lastFlag) {
        float s = 0.f;
#pragma unroll
        for (int i = 0; i < 4; ++i) {
            int j = tid + i * 512;
            int cnt = atomicAdd(&counts[j], 0);      // coherent read
            float p = (float)cnt * (1.0f / 65536.0f);
            s += p * logf(p + 1e-10f);
        }
#pragma unroll
        for (int off = 32; off > 0; off >>= 1) s += __shfl_xor(s, off);
        if (lane == 0) wls[w] = s;
        __syncthreads();
        if (tid == 0) {
            float tot = 0.f;
#pragma unroll
            for (int i = 0; i < 8; ++i) tot += wls[i];
            float L = atomicAdd(lossSum, 0.f) * (1.0f / (float)QST_SIZE);
            outQ[QST_SIZE + 0] = 0.25f * L;   // commitment_loss
            outQ[QST_SIZE + 1] = L;           // codebook_loss
            outQ[QST_SIZE + 2] = expf(-tot);  // perplexity
        }
    }
}

extern "C" void kernel_launch(void* const* d_in, const int* in_sizes, int n_in,
                              void* d_out, int out_size, void* d_ws, size_t ws_size,
                              hipStream_t stream) {
    const float* x    = (const float*)d_in[0];
    const float* emb  = (const float*)d_in[1];
    const float* mask = (const float*)d_in[2];
    float* out = (float*)d_out;

    _Float16* eh     = (_Float16*)((char*)d_ws + WS_EH);
    _Float16* el     = (_Float16*)((char*)d_ws + WS_EL);
    float* d0        = (float*)((char*)d_ws + WS_D0);
    int*   counts    = (int*)((char*)d_ws + WS_CNT);
    float* lossSum   = (float*)((char*)d_ws + WS_LOSS);
    unsigned* doneCt = (unsigned*)((char*)d_ws + WS_DONE);

    prep_kernel<<<dim3(32), dim3(256), 0, stream>>>(emb, eh, el, d0, counts, lossSum, doneCt);
    vq_main<<<dim3(NTOK / TOK_TILE, NCB), dim3(512), 0, stream>>>(
        x, emb, mask, eh, el, d0, counts, lossSum, doneCt, out, out + IDX_OFF);
}